// Round 6
// baseline (562.010 us; speedup 1.0000x reference)
//
#include <hip/hip_runtime.h>
#include <hip/hip_bf16.h>
#include <stdint.h>

#define T_TOK 2048
#define HDIM  1024
#define IDIM  3584
#define NEXP  8
#define NROWS 4096   // T_TOK * TOP_K

typedef __attribute__((ext_vector_type(8))) short bf16x8;
typedef __attribute__((ext_vector_type(4))) float f32x4;

typedef __attribute__((address_space(3))) unsigned lds_u32;
typedef const __attribute__((address_space(1))) unsigned glb_u32;

__device__ __forceinline__ unsigned short f2bf(float f){
  union { float f; unsigned u; } v; v.f = f;
  unsigned r = v.u + 0x7FFFu + ((v.u >> 16) & 1u);
  return (unsigned short)(r >> 16);
}
__device__ __forceinline__ bf16x8 pack8(float4 lo, float4 hi){
  union { __hip_bfloat162 b2[4]; bf16x8 v; } u;
  u.b2[0] = __float22bfloat162_rn(float2{lo.x, lo.y});
  u.b2[1] = __float22bfloat162_rn(float2{lo.z, lo.w});
  u.b2[2] = __float22bfloat162_rn(float2{hi.x, hi.y});
  u.b2[3] = __float22bfloat162_rn(float2{hi.z, hi.w});
  return u.v;
}

// ---------------- Kernel 1: RMSNorm + router ----------------
__global__ __launch_bounds__(256) void k_rms_router(
    const float* __restrict__ x, const float* __restrict__ rmsw,
    const float* __restrict__ gw, unsigned short* __restrict__ h_bf,
    int* __restrict__ topk_i, float* __restrict__ topk_w, int* __restrict__ count)
{
  const int t = blockIdx.x, tid = threadIdx.x;
  const int lane = tid & 63, wid = tid >> 6;
  float4 x4 = reinterpret_cast<const float4*>(x)[t*256 + tid];
  float ss = x4.x*x4.x + x4.y*x4.y + x4.z*x4.z + x4.w*x4.w;
  #pragma unroll
  for (int o = 32; o >= 1; o >>= 1) ss += __shfl_xor(ss, o);
  __shared__ float sred[4];
  __shared__ float slog[32];
  if (lane == 0) sred[wid] = ss;
  __syncthreads();
  float inv = rsqrtf((sred[0]+sred[1]+sred[2]+sred[3]) * (1.0f/HDIM) + 1e-6f);
  float4 w4 = reinterpret_cast<const float4*>(rmsw)[tid];
  float h0 = x4.x*inv*w4.x, h1 = x4.y*inv*w4.y, h2 = x4.z*inv*w4.z, h3 = x4.w*inv*w4.w;
  ushort4 hb; hb.x = f2bf(h0); hb.y = f2bf(h1); hb.z = f2bf(h2); hb.w = f2bf(h3);
  reinterpret_cast<ushort4*>(h_bf)[t*256 + tid] = hb;
  #pragma unroll
  for (int e = 0; e < NEXP; e++){
    float4 g4 = reinterpret_cast<const float4*>(gw)[e*256 + tid];
    float v = h0*g4.x + h1*g4.y + h2*g4.z + h3*g4.w;
    #pragma unroll
    for (int o = 32; o >= 1; o >>= 1) v += __shfl_xor(v, o);
    if (lane == 0) slog[e*4 + wid] = v;
  }
  __syncthreads();
  if (tid == 0){
    float lg[NEXP];
    #pragma unroll
    for (int e = 0; e < NEXP; e++) lg[e] = slog[e*4]+slog[e*4+1]+slog[e*4+2]+slog[e*4+3];
    int i0 = 0;
    for (int e = 1; e < NEXP; e++) if (lg[e] > lg[i0]) i0 = e;
    int i1 = -1;
    for (int e = 0; e < NEXP; e++){ if (e == i0) continue; if (i1 < 0 || lg[e] > lg[i1]) i1 = e; }
    float m  = fmaxf(lg[i0], lg[i1]);
    float e0 = expf(lg[i0]-m), e1 = expf(lg[i1]-m);
    float s  = e0 + e1;
    topk_i[t*2] = i0; topk_i[t*2+1] = i1;
    topk_w[t*2] = e0/s; topk_w[t*2+1] = e1/s;
    atomicAdd(&count[i0], 1); atomicAdd(&count[i1], 1);
  }
}

// ---------------- Kernel 2: offsets ----------------
__global__ void k_scan(const int* __restrict__ count, int* __restrict__ offset){
  if (threadIdx.x == 0){
    int o = 0;
    for (int e = 0; e < NEXP; e++){ offset[e] = o; o += count[e]; }
  }
}

// ---------------- Kernel 3: scatter ----------------
__global__ __launch_bounds__(256) void k_scatter(
    const int* __restrict__ topk_i, const float* __restrict__ topk_w,
    const int* __restrict__ offset, int* __restrict__ cursor,
    int* __restrict__ token_of_row, float* __restrict__ wrow, int* __restrict__ slot_of)
{
  int t = blockIdx.x*256 + threadIdx.x;
  if (t >= T_TOK) return;
  #pragma unroll
  for (int k = 0; k < 2; k++){
    int e = topk_i[t*2+k];
    int pos = atomicAdd(&cursor[e], 1);
    int row = offset[e] + pos;
    token_of_row[row] = t;
    wrow[row] = topk_w[t*2+k];
    slot_of[t*2+k] = row;
  }
}

// ---------------- Kernel 4: fused w1/w3 GEMM + SwiGLU ----------------
// 128x128 tile, BK=32, 256 thr (4 waves 2x2, wave tile 64x64).
// A bf16 + B fp32 BOTH staged via global_load_lds (pre-swizzled sources).
// fp32->bf16 cvt in inner loop. One barrier per K-step, dbuf.
__global__ __launch_bounds__(256, 2) void k_mlp_in(
    const unsigned short* __restrict__ h_bf, const float* __restrict__ w1,
    const float* __restrict__ w3, const int* __restrict__ token_of_row,
    const int* __restrict__ count, const int* __restrict__ offset,
    unsigned short* __restrict__ act)
{
  // XCD remap: nwg = 16*28*8 = 3584, chunk 448 => bz == XCD, tile fastest.
  int bx, by, bz;
  {
    int d = blockIdx.x + 16*(blockIdx.y + 28*blockIdx.z);
    int w = (d & 7)*448 + (d >> 3);
    bx = w & 15; int r = w >> 4; by = r % 28; bz = r / 28;
  }
  const int e = bz, tile = bx;
  const int cnt = count[e];
  if (tile*128 >= cnt) return;
  const int off = offset[e], row0 = off + tile*128, rend = off + cnt;
  const int col0 = by*128;
  const int tid = threadIdx.x, lane = tid & 63, wave = tid >> 6;
  const int wave_r = wave >> 1, wave_c = wave & 1;

  __shared__ __align__(16) char sA [2*8192];    // [buf][128 rows][32 k] bf16, slot^(row&3)
  __shared__ __align__(16) char sB1[2*16384];   // [buf][128 cols][32 k] fp32, slot^(col&7)
  __shared__ __align__(16) char sB3[2*16384];

  // ---- A staging sources: 2 issues, row = i*64 + wave*16 + (lane>>2), phys slot lane&3
  const unsigned short* aptr[2];
  {
    int asl = (lane & 3) ^ ((lane >> 2) & 3);   // pre-swizzled logical slot
    #pragma unroll
    for (int i = 0; i < 2; i++){
      int row = i*64 + wave*16 + (lane >> 2);
      int tok = token_of_row[min(row0 + row, NROWS-1)];
      aptr[i] = h_bf + (size_t)tok*HDIM + asl*8;
    }
  }
  #define ISSUE_A(kk, b) { _Pragma("unroll")                                         \
    for (int i = 0; i < 2; i++)                                                      \
      __builtin_amdgcn_global_load_lds((glb_u32*)(const void*)(aptr[i] + (kk)*32),   \
          (lds_u32*)(void*)(sA + (b)*8192 + i*4096 + wave*1024), 16, 0, 0); }

  // ---- B staging sources: 4 issues each, col = i*32 + wave*8 + (lane>>3), slot lane&7
  const float* b1ptr[4];
  const float* b3ptr[4];
  {
    int bsl = (lane & 7) ^ ((lane >> 3) & 7);
    #pragma unroll
    for (int i = 0; i < 4; i++){
      int col = col0 + i*32 + wave*8 + (lane >> 3);
      b1ptr[i] = w1 + (size_t)(e*IDIM + col)*HDIM + bsl*4;
      b3ptr[i] = w3 + (size_t)(e*IDIM + col)*HDIM + bsl*4;
    }
  }
  #define ISSUE_B(kk, b) { _Pragma("unroll")                                         \
    for (int i = 0; i < 4; i++){                                                     \
      __builtin_amdgcn_global_load_lds((glb_u32*)(const void*)(b1ptr[i] + (kk)*32),  \
          (lds_u32*)(void*)(sB1 + (b)*16384 + i*4096 + wave*1024), 16, 0, 0);        \
      __builtin_amdgcn_global_load_lds((glb_u32*)(const void*)(b3ptr[i] + (kk)*32),  \
          (lds_u32*)(void*)(sB3 + (b)*16384 + i*4096 + wave*1024), 16, 0, 0);        \
    } }

  f32x4 acc1[4][4], acc3[4][4];
  #pragma unroll
  for (int m = 0; m < 4; m++)
    #pragma unroll
    for (int n = 0; n < 4; n++){
      acc1[m][n] = (f32x4){0.f,0.f,0.f,0.f};
      acc3[m][n] = (f32x4){0.f,0.f,0.f,0.f};
    }

  const int aoff = ((lane >> 4) ^ (lane & 3)) << 4;              // A phys slot bytes
  const int bp0  = (((lane >> 4)*2)     ^ (lane & 7)) << 4;      // B phys slot bytes (lo)
  const int bp1  = (((lane >> 4)*2 + 1) ^ (lane & 7)) << 4;      // B phys slot bytes (hi)

  ISSUE_A(0, 0);
  ISSUE_B(0, 0);
  for (int kk = 0; kk < HDIM/32; kk++){
    const int b = kk & 1;
    __syncthreads();                       // drains vmcnt: buf b ready
    if (kk + 1 < HDIM/32){ ISSUE_A(kk+1, b^1); ISSUE_B(kk+1, b^1); }
    bf16x8 af[4];
    #pragma unroll
    for (int m = 0; m < 4; m++){
      int row = wave_r*64 + m*16 + (lane & 15);
      af[m] = *reinterpret_cast<const bf16x8*>(sA + b*8192 + row*64 + aoff);
    }
    #pragma unroll
    for (int n = 0; n < 4; n++){
      int col = wave_c*64 + n*16 + (lane & 15);
      const char* base1 = sB1 + b*16384 + col*128;
      const char* base3 = sB3 + b*16384 + col*128;
      float4 lo1 = *reinterpret_cast<const float4*>(base1 + bp0);
      float4 hi1 = *reinterpret_cast<const float4*>(base1 + bp1);
      float4 lo3 = *reinterpret_cast<const float4*>(base3 + bp0);
      float4 hi3 = *reinterpret_cast<const float4*>(base3 + bp1);
      bf16x8 f1 = pack8(lo1, hi1);
      bf16x8 f3 = pack8(lo3, hi3);
      #pragma unroll
      for (int m = 0; m < 4; m++){
        acc1[m][n] = __builtin_amdgcn_mfma_f32_16x16x32_bf16(af[m], f1, acc1[m][n], 0,0,0);
        acc3[m][n] = __builtin_amdgcn_mfma_f32_16x16x32_bf16(af[m], f3, acc3[m][n], 0,0,0);
      }
    }
  }

  // epilogue: silu(a)*g -> bf16
  const int lcol = lane & 15, lrow4 = (lane >> 4) * 4;
  #pragma unroll
  for (int m = 0; m < 4; m++){
    #pragma unroll
    for (int n = 0; n < 4; n++){
      int gcol = col0 + wave_c*64 + n*16 + lcol;
      #pragma unroll
      for (int r = 0; r < 4; r++){
        int grow = row0 + wave_r*64 + m*16 + lrow4 + r;
        if (grow < rend){
          float a = acc1[m][n][r], g = acc3[m][n][r];
          float sig = 1.0f / (1.0f + __expf(-a));
          act[(size_t)grow*IDIM + gcol] = f2bf(a * sig * g);
        }
      }
    }
  }
  #undef ISSUE_A
  #undef ISSUE_B
}

// ---------------- Kernel 5: w2 GEMM ----------------
// Same structure, single B, K=3584 (112 steps). LDS 48KB -> 3 blocks/CU.
__global__ __launch_bounds__(256, 3) void k_mlp_out(
    const unsigned short* __restrict__ act, const float* __restrict__ w2,
    const float* __restrict__ wrow, const int* __restrict__ count,
    const int* __restrict__ offset, float* __restrict__ eo)
{
  // XCD remap: nwg = 16*8*8 = 1024, chunk 128 => bz == XCD.
  int bx, by, bz;
  {
    int d = blockIdx.x + 16*(blockIdx.y + 8*blockIdx.z);
    int w = (d & 7)*128 + (d >> 3);
    bx = w & 15; int r = w >> 4; by = r & 7; bz = r >> 3;
  }
  const int e = bz, tile = bx;
  const int cnt = count[e];
  if (tile*128 >= cnt) return;
  const int off = offset[e], row0 = off + tile*128, rend = off + cnt;
  const int col0 = by*128;
  const int tid = threadIdx.x, lane = tid & 63, wave = tid >> 6;
  const int wave_r = wave >> 1, wave_c = wave & 1;

  __shared__ __align__(16) char sA[2*8192];
  __shared__ __align__(16) char sB[2*16384];

  const unsigned short* aptr[2];
  {
    int asl = (lane & 3) ^ ((lane >> 2) & 3);
    #pragma unroll
    for (int i = 0; i < 2; i++){
      int row = min(row0 + i*64 + wave*16 + (lane >> 2), NROWS-1);
      aptr[i] = act + (size_t)row*IDIM + asl*8;
    }
  }
  #define ISSUE_A(kk, b) { _Pragma("unroll")                                         \
    for (int i = 0; i < 2; i++)                                                      \
      __builtin_amdgcn_global_load_lds((glb_u32*)(const void*)(aptr[i] + (kk)*32),   \
          (lds_u32*)(void*)(sA + (b)*8192 + i*4096 + wave*1024), 16, 0, 0); }

  const float* bptr[4];
  {
    int bsl = (lane & 7) ^ ((lane >> 3) & 7);
    #pragma unroll
    for (int i = 0; i < 4; i++){
      int col = col0 + i*32 + wave*8 + (lane >> 3);
      bptr[i] = w2 + (size_t)(e*HDIM + col)*IDIM + bsl*4;
    }
  }
  #define ISSUE_B(kk, b) { _Pragma("unroll")                                         \
    for (int i = 0; i < 4; i++)                                                      \
      __builtin_amdgcn_global_load_lds((glb_u32*)(const void*)(bptr[i] + (kk)*32),   \
          (lds_u32*)(void*)(sB + (b)*16384 + i*4096 + wave*1024), 16, 0, 0); }

  f32x4 acc[4][4];
  #pragma unroll
  for (int m = 0; m < 4; m++)
    #pragma unroll
    for (int n = 0; n < 4; n++) acc[m][n] = (f32x4){0.f,0.f,0.f,0.f};

  const int aoff = ((lane >> 4) ^ (lane & 3)) << 4;
  const int bp0  = (((lane >> 4)*2)     ^ (lane & 7)) << 4;
  const int bp1  = (((lane >> 4)*2 + 1) ^ (lane & 7)) << 4;

  ISSUE_A(0, 0);
  ISSUE_B(0, 0);
  for (int kk = 0; kk < IDIM/32; kk++){
    const int b = kk & 1;
    __syncthreads();
    if (kk + 1 < IDIM/32){ ISSUE_A(kk+1, b^1); ISSUE_B(kk+1, b^1); }
    bf16x8 af[4];
    #pragma unroll
    for (int m = 0; m < 4; m++){
      int row = wave_r*64 + m*16 + (lane & 15);
      af[m] = *reinterpret_cast<const bf16x8*>(sA + b*8192 + row*64 + aoff);
    }
    #pragma unroll
    for (int n = 0; n < 4; n++){
      int col = wave_c*64 + n*16 + (lane & 15);
      const char* base = sB + b*16384 + col*128;
      float4 lo = *reinterpret_cast<const float4*>(base + bp0);
      float4 hi = *reinterpret_cast<const float4*>(base + bp1);
      bf16x8 fb = pack8(lo, hi);
      #pragma unroll
      for (int m = 0; m < 4; m++)
        acc[m][n] = __builtin_amdgcn_mfma_f32_16x16x32_bf16(af[m], fb, acc[m][n], 0,0,0);
    }
  }

  const int lcol = lane & 15, lrow4 = (lane >> 4) * 4;
  #pragma unroll
  for (int m = 0; m < 4; m++){
    #pragma unroll
    for (int n = 0; n < 4; n++){
      int gcol = col0 + wave_c*64 + n*16 + lcol;
      #pragma unroll
      for (int r = 0; r < 4; r++){
        int grow = row0 + wave_r*64 + m*16 + lrow4 + r;
        if (grow < rend){
          eo[(size_t)grow*HDIM + gcol] = acc[m][n][r] * wrow[grow];
        }
      }
    }
  }
  #undef ISSUE_A
  #undef ISSUE_B
}

// ---------------- Kernel 6: combine + residual ----------------
__global__ __launch_bounds__(256) void k_combine(
    const float* __restrict__ x, const float* __restrict__ eo,
    const int* __restrict__ slot_of, float* __restrict__ out)
{
  const int t = blockIdx.x, tid = threadIdx.x;
  const int s0 = slot_of[t*2], s1 = slot_of[t*2+1];
  float4 xv = reinterpret_cast<const float4*>(x)[t*256 + tid];
  float4 a  = reinterpret_cast<const float4*>(eo)[s0*256 + tid];
  float4 b  = reinterpret_cast<const float4*>(eo)[s1*256 + tid];
  float4 ov;
  ov.x = xv.x + a.x + b.x;
  ov.y = xv.y + a.y + b.y;
  ov.z = xv.z + a.z + b.z;
  ov.w = xv.w + a.w + b.w;
  reinterpret_cast<float4*>(out)[t*256 + tid] = ov;
}

extern "C" void kernel_launch(void* const* d_in, const int* in_sizes, int n_in,
                              void* d_out, int out_size, void* d_ws, size_t ws_size,
                              hipStream_t stream)
{
  const float* x    = (const float*)d_in[0];
  const float* rmsw = (const float*)d_in[1];
  const float* gw   = (const float*)d_in[2];
  const float* w1   = (const float*)d_in[3];
  const float* w2   = (const float*)d_in[4];
  const float* w3   = (const float*)d_in[5];
  float* out = (float*)d_out;

  char* ws = (char*)d_ws;
  size_t o = 0;
  auto alloc = [&](size_t bytes) -> void* {
    void* p = ws + o;
    o += (bytes + 255) & ~(size_t)255;
    return p;
  };
  unsigned short* h_bf   = (unsigned short*)alloc((size_t)T_TOK*HDIM*2);
  int*   topk_i          = (int*)  alloc(T_TOK*2*4);
  float* topk_w          = (float*)alloc(T_TOK*2*4);
  int*   counters        = (int*)  alloc(64*4);   // count[8], cursor[8], offset[8]
  int*   token_of_row    = (int*)  alloc(NROWS*4);
  float* wrow            = (float*)alloc(NROWS*4);
  int*   slot_of         = (int*)  alloc(T_TOK*2*4);
  unsigned short* act    = (unsigned short*)alloc((size_t)NROWS*IDIM*2);
  float* eo              = (float*)alloc((size_t)NROWS*HDIM*4);
  int* count  = counters;
  int* cursor = counters + 8;
  int* offset = counters + 16;

  hipMemsetAsync(counters, 0, 64*4, stream);
  k_rms_router<<<T_TOK, 256, 0, stream>>>(x, rmsw, gw, h_bf, topk_i, topk_w, count);
  k_scan<<<1, 64, 0, stream>>>(count, offset);
  k_scatter<<<(T_TOK+255)/256, 256, 0, stream>>>(topk_i, topk_w, offset, cursor,
                                                 token_of_row, wrow, slot_of);
  k_mlp_in <<<dim3(16, 28, 8), 256, 0, stream>>>(h_bf, w1, w3, token_of_row,
                                                 count, offset, act);
  k_mlp_out<<<dim3(16, 8, 8), 256, 0, stream>>>(act, w2, wrow, count, offset, eo);
  k_combine<<<T_TOK, 256, 0, stream>>>(x, eo, slot_of, out);
}

// Round 7
// 388.692 us; speedup vs baseline: 1.4459x; 1.4459x over previous
//
#include <hip/hip_runtime.h>
#include <hip/hip_bf16.h>
#include <stdint.h>

#define T_TOK 2048
#define HDIM  1024
#define IDIM  3584
#define NEXP  8
#define NROWS 4096   // T_TOK * TOP_K

typedef __attribute__((ext_vector_type(8))) short bf16x8;
typedef __attribute__((ext_vector_type(4))) float f32x4;

typedef __attribute__((address_space(3))) unsigned lds_u32;
typedef const __attribute__((address_space(1))) unsigned glb_u32;

__device__ __forceinline__ unsigned short f2bf(float f){
  union { float f; unsigned u; } v; v.f = f;
  unsigned r = v.u + 0x7FFFu + ((v.u >> 16) & 1u);   // RNE
  return (unsigned short)(r >> 16);
}
__device__ __forceinline__ bf16x8 pack8(float4 lo, float4 hi){
  union { __hip_bfloat162 b2[4]; bf16x8 v; } u;
  u.b2[0] = __float22bfloat162_rn(float2{lo.x, lo.y});
  u.b2[1] = __float22bfloat162_rn(float2{lo.z, lo.w});
  u.b2[2] = __float22bfloat162_rn(float2{hi.x, hi.y});
  u.b2[3] = __float22bfloat162_rn(float2{hi.z, hi.w});
  return u.v;
}

// raw barrier discipline: lgkmcnt(0) (my LDS writes landed) + s_barrier,
// NO vmcnt drain -- global loads stay in flight across the barrier.
__device__ __forceinline__ void pipe_barrier(){
  asm volatile("s_waitcnt lgkmcnt(0)" ::: "memory");
  __builtin_amdgcn_sched_barrier(0);
  __builtin_amdgcn_s_barrier();
  __builtin_amdgcn_sched_barrier(0);
}

// ---------------- Kernel 1: RMSNorm + router ----------------
__global__ __launch_bounds__(256) void k_rms_router(
    const float* __restrict__ x, const float* __restrict__ rmsw,
    const float* __restrict__ gw, unsigned short* __restrict__ h_bf,
    int* __restrict__ topk_i, float* __restrict__ topk_w, int* __restrict__ count)
{
  const int t = blockIdx.x, tid = threadIdx.x;
  const int lane = tid & 63, wid = tid >> 6;
  float4 x4 = reinterpret_cast<const float4*>(x)[t*256 + tid];
  float ss = x4.x*x4.x + x4.y*x4.y + x4.z*x4.z + x4.w*x4.w;
  #pragma unroll
  for (int o = 32; o >= 1; o >>= 1) ss += __shfl_xor(ss, o);
  __shared__ float sred[4];
  __shared__ float slog[32];
  if (lane == 0) sred[wid] = ss;
  __syncthreads();
  float inv = rsqrtf((sred[0]+sred[1]+sred[2]+sred[3]) * (1.0f/HDIM) + 1e-6f);
  float4 w4 = reinterpret_cast<const float4*>(rmsw)[tid];
  float h0 = x4.x*inv*w4.x, h1 = x4.y*inv*w4.y, h2 = x4.z*inv*w4.z, h3 = x4.w*inv*w4.w;
  ushort4 hb; hb.x = f2bf(h0); hb.y = f2bf(h1); hb.z = f2bf(h2); hb.w = f2bf(h3);
  reinterpret_cast<ushort4*>(h_bf)[t*256 + tid] = hb;
  #pragma unroll
  for (int e = 0; e < NEXP; e++){
    float4 g4 = reinterpret_cast<const float4*>(gw)[e*256 + tid];
    float v = h0*g4.x + h1*g4.y + h2*g4.z + h3*g4.w;
    #pragma unroll
    for (int o = 32; o >= 1; o >>= 1) v += __shfl_xor(v, o);
    if (lane == 0) slog[e*4 + wid] = v;
  }
  __syncthreads();
  if (tid == 0){
    float lg[NEXP];
    #pragma unroll
    for (int e = 0; e < NEXP; e++) lg[e] = slog[e*4]+slog[e*4+1]+slog[e*4+2]+slog[e*4+3];
    int i0 = 0;
    for (int e = 1; e < NEXP; e++) if (lg[e] > lg[i0]) i0 = e;   // ties -> lowest index
    int i1 = -1;
    for (int e = 0; e < NEXP; e++){ if (e == i0) continue; if (i1 < 0 || lg[e] > lg[i1]) i1 = e; }
    float m  = fmaxf(lg[i0], lg[i1]);
    float e0 = expf(lg[i0]-m), e1 = expf(lg[i1]-m);
    float s  = e0 + e1;
    topk_i[t*2] = i0; topk_i[t*2+1] = i1;
    topk_w[t*2] = e0/s; topk_w[t*2+1] = e1/s;
    atomicAdd(&count[i0], 1); atomicAdd(&count[i1], 1);
  }
}

// ---------------- Kernel 2: offsets ----------------
__global__ void k_scan(const int* __restrict__ count, int* __restrict__ offset){
  if (threadIdx.x == 0){
    int o = 0;
    for (int e = 0; e < NEXP; e++){ offset[e] = o; o += count[e]; }
  }
}

// ---------------- Kernel 3: scatter ----------------
__global__ __launch_bounds__(256) void k_scatter(
    const int* __restrict__ topk_i, const float* __restrict__ topk_w,
    const int* __restrict__ offset, int* __restrict__ cursor,
    int* __restrict__ token_of_row, float* __restrict__ wrow, int* __restrict__ slot_of)
{
  int t = blockIdx.x*256 + threadIdx.x;
  if (t >= T_TOK) return;
  #pragma unroll
  for (int k = 0; k < 2; k++){
    int e = topk_i[t*2+k];
    int pos = atomicAdd(&cursor[e], 1);
    int row = offset[e] + pos;
    token_of_row[row] = t;
    wrow[row] = topk_w[t*2+k];
    slot_of[t*2+k] = row;
  }
}

// ---------------- Kernel 4: fused w1/w3 GEMM + SwiGLU ----------------
// R2 geometry (proven 0-conflict): 128 rows x 64 cols dual-gemm, BK=64, 4 waves 2x2.
// NEW: A via global_load_lds into dbuf sA; B reg-staged fp32->bf16 (single buf);
// raw barriers, counted vmcnt -- loads never drained at barriers.
__global__ __launch_bounds__(256, 3) void k_mlp_in(
    const unsigned short* __restrict__ h_bf, const float* __restrict__ w1,
    const float* __restrict__ w3, const int* __restrict__ token_of_row,
    const int* __restrict__ count, const int* __restrict__ offset,
    unsigned short* __restrict__ act)
{
  // XCD-chunked bijective remap: nwg = 16*56*8 = 7168, chunk = 896.
  int bx, by, bz;
  {
    int d = blockIdx.x + 16*(blockIdx.y + 56*blockIdx.z);
    int w = (d & 7)*896 + (d >> 3);
    bx = w & 15; int r = w >> 4; by = r % 56; bz = r / 56;
  }
  const int e = bz, tile = bx;
  const int cnt = count[e];
  if (tile * 128 >= cnt) return;          // whole block exits together (no partial barrier)
  const int off  = offset[e];
  const int row0 = off + tile*128;
  const int rend = off + cnt;
  const int col0 = by * 64;
  const int tid = threadIdx.x, lane = tid & 63, wid = tid >> 6;
  const int wave_r = wid >> 1, wave_c = wid & 1;

  __shared__ __align__(16) char sA [2*16384];  // dbuf: 128 rows x 64 bf16, swizzled slots
  __shared__ __align__(16) char sB1[64*128];   // 64 cols x 64 bf16
  __shared__ __align__(16) char sB2[64*128];

  const int arow_base = tid >> 3;   // 0..31
  const int kseg = tid & 7;
  // A sources: pre-swizzled per-lane global address; LDS dest is tid*16-linear.
  const unsigned short* asrc[4];
  #pragma unroll
  for (int j = 0; j < 4; j++){
    int r = arow_base + 32*j;
    int tok = token_of_row[min(row0 + r, NROWS-1)];
    asrc[j] = h_bf + (size_t)tok*HDIM + ((kseg ^ (arow_base & 7)))*8;
  }
  #define ISSUE_A(kk, b) { _Pragma("unroll")                                         \
    for (int j = 0; j < 4; j++)                                                      \
      __builtin_amdgcn_global_load_lds((glb_u32*)(const void*)(asrc[j] + (kk)*64),   \
          (lds_u32*)(void*)(sA + (b)*16384 + j*4096 + tid*16), 16, 0, 0); }

  const float* w1base = w1 + (size_t)e*IDIM*HDIM + (size_t)(col0 + arow_base)*HDIM + kseg*8;
  const float* w3base = w3 + (size_t)e*IDIM*HDIM + (size_t)(col0 + arow_base)*HDIM + kseg*8;

  float4 pb1[2][2], pb3[2][2];
  #define LOAD_B(kk) { _Pragma("unroll")                                             \
    for (int j = 0; j < 2; j++){                                                     \
      const float4* p1 = reinterpret_cast<const float4*>(w1base + (size_t)(32*j)*HDIM + (kk)*64); \
      const float4* p3 = reinterpret_cast<const float4*>(w3base + (size_t)(32*j)*HDIM + (kk)*64); \
      pb1[j][0] = p1[0]; pb1[j][1] = p1[1];                                          \
      pb3[j][0] = p3[0]; pb3[j][1] = p3[1];                                          \
    } }

  const int bswz = (kseg ^ (arow_base & 7)) << 4;   // same for both j (32j % 8 == 0)
  #define STORE_B() { _Pragma("unroll")                                              \
    for (int j = 0; j < 2; j++){                                                     \
      *reinterpret_cast<bf16x8*>(sB1 + (arow_base + 32*j)*128 + bswz) = pack8(pb1[j][0], pb1[j][1]); \
      *reinterpret_cast<bf16x8*>(sB2 + (arow_base + 32*j)*128 + bswz) = pack8(pb3[j][0], pb3[j][1]); \
    } }

  f32x4 acc_a[4][2], acc_g[4][2];
  #pragma unroll
  for (int m = 0; m < 4; m++)
    #pragma unroll
    for (int n = 0; n < 2; n++){
      acc_a[m][n] = (f32x4){0.f,0.f,0.f,0.f};
      acc_g[m][n] = (f32x4){0.f,0.f,0.f,0.f};
    }

  #define COMPUTE(b) { _Pragma("unroll")                                             \
    for (int ki = 0; ki < 2; ki++){                                                  \
      bf16x8 af[4];                                                                  \
      _Pragma("unroll")                                                              \
      for (int m = 0; m < 4; m++){                                                   \
        int row = wave_r*64 + m*16 + (lane&15);                                      \
        int slot = ki*4 + (lane>>4);                                                 \
        af[m] = *reinterpret_cast<const bf16x8*>(sA + (b)*16384 + row*128 + ((slot ^ (row&7))<<4)); \
      }                                                                              \
      _Pragma("unroll")                                                              \
      for (int n = 0; n < 2; n++){                                                   \
        int col = wave_c*32 + n*16 + (lane&15);                                      \
        int slot = ki*4 + (lane>>4);                                                 \
        bf16x8 b1 = *reinterpret_cast<const bf16x8*>(sB1 + col*128 + ((slot ^ (col&7))<<4)); \
        bf16x8 b2 = *reinterpret_cast<const bf16x8*>(sB2 + col*128 + ((slot ^ (col&7))<<4)); \
        _Pragma("unroll")                                                            \
        for (int m = 0; m < 4; m++){                                                 \
          acc_a[m][n] = __builtin_amdgcn_mfma_f32_16x16x32_bf16(af[m], b1, acc_a[m][n], 0,0,0); \
          acc_g[m][n] = __builtin_amdgcn_mfma_f32_16x16x32_bf16(af[m], b2, acc_g[m][n], 0,0,0); \
        }                                                                            \
      }                                                                              \
    } }

  // prologue: A before B (vmcnt FIFO: waiting any B reg implies A landed)
  ISSUE_A(0, 0);
  asm volatile("" ::: "memory");
  LOAD_B(0);
  for (int kk = 0; kk < HDIM/64; kk++){
    const int b = kk & 1;
    STORE_B();                      // per-reg vmcnt waits on B(kk) => A(kk) in LDS
    pipe_barrier();                 // publish sA[b] + sB; loads NOT drained
    if (kk + 1 < HDIM/64){
      ISSUE_A(kk+1, b^1);           // into other buffer, full step of latency cover
      asm volatile("" ::: "memory");
      LOAD_B(kk+1);
    }
    asm volatile("s_waitcnt vmcnt(12)" ::: "memory");  // defensive: A(kk) complete
    __builtin_amdgcn_sched_barrier(0);
    COMPUTE(b);
    pipe_barrier();                 // protect sB overwrite next iteration
  }

  // epilogue: silu(a)*g -> bf16
  const int lcol = lane & 15, lrow4 = (lane >> 4) * 4;
  #pragma unroll
  for (int m = 0; m < 4; m++){
    #pragma unroll
    for (int n = 0; n < 2; n++){
      int gcol = col0 + wave_c*32 + n*16 + lcol;
      #pragma unroll
      for (int r = 0; r < 4; r++){
        int grow = row0 + wave_r*64 + m*16 + lrow4 + r;
        if (grow < rend){
          float a = acc_a[m][n][r], g = acc_g[m][n][r];
          float sig = 1.0f / (1.0f + __expf(-a));
          act[(size_t)grow*IDIM + gcol] = f2bf(a * sig * g);
        }
      }
    }
  }
  #undef ISSUE_A
  #undef LOAD_B
  #undef STORE_B
  #undef COMPUTE
}

// ---------------- Kernel 5: w2 GEMM (same discipline) ----------------
__global__ __launch_bounds__(256, 4) void k_mlp_out(
    const unsigned short* __restrict__ act, const float* __restrict__ w2,
    const float* __restrict__ wrow, const int* __restrict__ count,
    const int* __restrict__ offset, float* __restrict__ eo)
{
  // XCD-chunked bijective remap: nwg = 16*16*8 = 2048, chunk = 256.
  int bx, by, bz;
  {
    int d = blockIdx.x + 16*(blockIdx.y + 16*blockIdx.z);
    int w = (d & 7)*256 + (d >> 3);
    bx = w & 15; int r = w >> 4; by = r & 15; bz = r >> 4;
  }
  const int e = bz, tile = bx;
  const int cnt = count[e];
  if (tile*128 >= cnt) return;
  const int off = offset[e], row0 = off + tile*128, rend = off + cnt;
  const int col0 = by * 64;
  const int tid = threadIdx.x, lane = tid & 63, wid = tid >> 6;
  const int wave_r = wid >> 1, wave_c = wid & 1;

  __shared__ __align__(16) char sA[2*16384];
  __shared__ __align__(16) char sB[64*128];

  const int arow_base = tid >> 3, kseg = tid & 7;
  const unsigned short* asrc[4];
  #pragma unroll
  for (int j = 0; j < 4; j++){
    int r = min(row0 + arow_base + 32*j, NROWS-1);
    asrc[j] = act + (size_t)r*IDIM + ((kseg ^ (arow_base & 7)))*8;
  }
  #define ISSUE_A(kk, b) { _Pragma("unroll")                                         \
    for (int j = 0; j < 4; j++)                                                      \
      __builtin_amdgcn_global_load_lds((glb_u32*)(const void*)(asrc[j] + (kk)*64),   \
          (lds_u32*)(void*)(sA + (b)*16384 + j*4096 + tid*16), 16, 0, 0); }

  const float* w2base = w2 + (size_t)e*HDIM*IDIM + (size_t)(col0 + arow_base)*IDIM + kseg*8;
  float4 pb[2][2];
  #define LOAD_B(kk) { _Pragma("unroll")                                             \
    for (int j = 0; j < 2; j++){                                                     \
      const float4* p = reinterpret_cast<const float4*>(w2base + (size_t)(32*j)*IDIM + (kk)*64); \
      pb[j][0] = p[0]; pb[j][1] = p[1];                                              \
    } }

  const int bswz = (kseg ^ (arow_base & 7)) << 4;
  #define STORE_B() { _Pragma("unroll")                                              \
    for (int j = 0; j < 2; j++)                                                      \
      *reinterpret_cast<bf16x8*>(sB + (arow_base + 32*j)*128 + bswz) = pack8(pb[j][0], pb[j][1]); }

  f32x4 acc[4][2];
  #pragma unroll
  for (int m = 0; m < 4; m++)
    #pragma unroll
    for (int n = 0; n < 2; n++) acc[m][n] = (f32x4){0.f,0.f,0.f,0.f};

  #define COMPUTE(b) { _Pragma("unroll")                                             \
    for (int ki = 0; ki < 2; ki++){                                                  \
      bf16x8 af[4];                                                                  \
      _Pragma("unroll")                                                              \
      for (int m = 0; m < 4; m++){                                                   \
        int row = wave_r*64 + m*16 + (lane&15);                                      \
        int slot = ki*4 + (lane>>4);                                                 \
        af[m] = *reinterpret_cast<const bf16x8*>(sA + (b)*16384 + row*128 + ((slot ^ (row&7))<<4)); \
      }                                                                              \
      _Pragma("unroll")                                                              \
      for (int n = 0; n < 2; n++){                                                   \
        int col = wave_c*32 + n*16 + (lane&15);                                      \
        int slot = ki*4 + (lane>>4);                                                 \
        bf16x8 fb = *reinterpret_cast<const bf16x8*>(sB + col*128 + ((slot ^ (col&7))<<4)); \
        _Pragma("unroll")                                                            \
        for (int m = 0; m < 4; m++)                                                  \
          acc[m][n] = __builtin_amdgcn_mfma_f32_16x16x32_bf16(af[m], fb, acc[m][n], 0,0,0); \
      }                                                                              \
    } }

  ISSUE_A(0, 0);
  asm volatile("" ::: "memory");
  LOAD_B(0);
  for (int kk = 0; kk < IDIM/64; kk++){
    const int b = kk & 1;
    STORE_B();
    pipe_barrier();
    if (kk + 1 < IDIM/64){
      ISSUE_A(kk+1, b^1);
      asm volatile("" ::: "memory");
      LOAD_B(kk+1);
    }
    asm volatile("s_waitcnt vmcnt(8)" ::: "memory");
    __builtin_amdgcn_sched_barrier(0);
    COMPUTE(b);
    pipe_barrier();
  }

  const int lcol = lane & 15, lrow4 = (lane >> 4) * 4;
  #pragma unroll
  for (int m = 0; m < 4; m++){
    #pragma unroll
    for (int n = 0; n < 2; n++){
      int gcol = col0 + wave_c*32 + n*16 + lcol;
      #pragma unroll
      for (int r = 0; r < 4; r++){
        int grow = row0 + wave_r*64 + m*16 + lrow4 + r;
        if (grow < rend){
          eo[(size_t)grow*HDIM + gcol] = acc[m][n][r] * wrow[grow];
        }
      }
    }
  }
  #undef ISSUE_A
  #undef LOAD_B
  #undef STORE_B
  #undef COMPUTE
}

// ---------------- Kernel 6: combine + residual ----------------
__global__ __launch_bounds__(256) void k_combine(
    const float* __restrict__ x, const float* __restrict__ eo,
    const int* __restrict__ slot_of, float* __restrict__ out)
{
  const int t = blockIdx.x, tid = threadIdx.x;
  const int s0 = slot_of[t*2], s1 = slot_of[t*2+1];
  float4 xv = reinterpret_cast<const float4*>(x)[t*256 + tid];
  float4 a  = reinterpret_cast<const float4*>(eo)[s0*256 + tid];
  float4 b  = reinterpret_cast<const float4*>(eo)[s1*256 + tid];
  float4 ov;
  ov.x = xv.x + a.x + b.x;
  ov.y = xv.y + a.y + b.y;
  ov.z = xv.z + a.z + b.z;
  ov.w = xv.w + a.w + b.w;
  reinterpret_cast<float4*>(out)[t*256 + tid] = ov;
}

extern "C" void kernel_launch(void* const* d_in, const int* in_sizes, int n_in,
                              void* d_out, int out_size, void* d_ws, size_t ws_size,
                              hipStream_t stream)
{
  const float* x    = (const float*)d_in[0];
  const float* rmsw = (const float*)d_in[1];
  const float* gw   = (const float*)d_in[2];
  const float* w1   = (const float*)d_in[3];
  const float* w2   = (const float*)d_in[4];
  const float* w3   = (const float*)d_in[5];
  float* out = (float*)d_out;

  char* ws = (char*)d_ws;
  size_t o = 0;
  auto alloc = [&](size_t bytes) -> void* {
    void* p = ws + o;
    o += (bytes + 255) & ~(size_t)255;
    return p;
  };
  unsigned short* h_bf   = (unsigned short*)alloc((size_t)T_TOK*HDIM*2);
  int*   topk_i          = (int*)  alloc(T_TOK*2*4);
  float* topk_w          = (float*)alloc(T_TOK*2*4);
  int*   counters        = (int*)  alloc(64*4);   // count[8], cursor[8], offset[8]
  int*   token_of_row    = (int*)  alloc(NROWS*4);
  float* wrow            = (float*)alloc(NROWS*4);
  int*   slot_of         = (int*)  alloc(T_TOK*2*4);
  unsigned short* act    = (unsigned short*)alloc((size_t)NROWS*IDIM*2);
  float* eo              = (float*)alloc((size_t)NROWS*HDIM*4);
  int* count  = counters;
  int* cursor = counters + 8;
  int* offset = counters + 16;

  hipMemsetAsync(counters, 0, 64*4, stream);
  k_rms_router<<<T_TOK, 256, 0, stream>>>(x, rmsw, gw, h_bf, topk_i, topk_w, count);
  k_scan<<<1, 64, 0, stream>>>(count, offset);
  k_scatter<<<(T_TOK+255)/256, 256, 0, stream>>>(topk_i, topk_w, offset, cursor,
                                                 token_of_row, wrow, slot_of);
  k_mlp_in <<<dim3(16, 56, 8), 256, 0, stream>>>(h_bf, w1, w3, token_of_row,
                                                 count, offset, act);
  k_mlp_out<<<dim3(16, 16, 8), 256, 0, stream>>>(act, w2, wrow, count, offset, eo);
  k_combine<<<T_TOK, 256, 0, stream>>>(x, eo, slot_of, out);
}